// Round 5
// baseline (50.375 us; speedup 1.0000x reference)
//
#include <hip/hip_runtime.h>
#include <stdint.h>

#define T_SZ 8192
#define NCH 96

typedef __attribute__((ext_vector_type(8))) short s8v;
typedef __attribute__((ext_vector_type(4))) float f4v;

// ---------- bf16 helpers ----------
__device__ __forceinline__ float lo_bf(uint32_t u){ return __uint_as_float(u << 16); }
__device__ __forceinline__ float hi_bf(uint32_t u){ return __uint_as_float(u & 0xffff0000u); }
__device__ __forceinline__ uint32_t f2bf(float f){
    uint32_t u = __float_as_uint(f);
    return (u + 0x7fffu + ((u >> 16) & 1u)) >> 16;   // RNE
}
__device__ __forceinline__ uint32_t pk2(float a, float b){ return f2bf(a) | (f2bf(b) << 16); }

// ---------- ws layout (bytes) ----------
#define WS_TOTAL_PAIRS 235520          // fused-fallback packed pairs
#define WD_OFF    942080               // DFT matrices W32[48][40] W64[80][72] W128[144][136]
#define WD_ELEMS  27264
#define WA_OFF    996608               // iDFT matrices A32[32][72] A64[64][104] A128[128][168]
#define WA_ELEMS  30464
#define WD64_U16   1920
#define WD128_U16  7680
#define WA64_U16   2304
#define WA128_U16  8960
#define WE_OFF   1057536               // expanded K2 B-matrices [115][64][128] u16, wk folded
#define WE_U32    471040               // 115*64*64
// wide-path scratch regions
#define XF32W    4194304
#define XF64W   14680064
#define XF128W  25165824
#define Y32W    35651584
#define Y64W    41943040
#define Y128W   50331648
#define WS_WIDE 58720256

// ================= prep: expanded weights + DFT/iDFT matrices =================
__global__ void prep_full(const float* __restrict__ kr, const float* __restrict__ ki,
                          char* __restrict__ ws)
{
    int idx = blockIdx.x * 256 + threadIdx.x;
    if (idx < WE_U32) {
        // WE[g][row=half*32+o][u32 c] ; half0: (kr, -ki)*wk, half1: (ki, kr)*wk
        int g = idx >> 12, r = idx & 4095;
        int row = r >> 6, c = r & 63;
        int o = row & 31, half = row >> 5;
        int bins, k;
        if (g < 17)      { bins = 17; k = g; }
        else if (g < 50) { bins = 33; k = g - 17; }
        else             { bins = 65; k = g - 50; }
        float s  = (k + 0.5f) * (33.0f / bins) - 0.5f;
        float fl = floorf(s);
        float w1 = s - fl;
        int i0 = min(max((int)fl, 0), 32);
        int i1 = min(max((int)fl + 1, 0), 32);
        int co = c * 32 + o;
        float r0 = kr[i0 * 2048 + co], r1 = kr[i1 * 2048 + co];
        float q0 = ki[i0 * 2048 + co], q1 = ki[i1 * 2048 + co];
        int N = bins * 2 - 2;
        float wk = (k == 0 || k == bins - 1) ? (1.0f / N) : (2.0f / N);  // pow2 -> exact
        float vr = fmaf(w1, r1 - r0, r0) * wk;
        float vi = fmaf(w1, q1 - q0, q0) * wk;
        ((uint32_t*)(ws + WE_OFF))[idx] = half ? pk2(vi, vr) : pk2(vr, -vi);
        return;
    }
    int e = idx - WE_U32;
    if (e < WD_ELEMS) {
        int N, NP, base;
        if (e < 1920)      { N = 32;  NP = 40;  base = 0; }
        else if (e < 7680) { N = 64;  NP = 72;  base = WD64_U16;  e -= 1920; }
        else               { N = 128; NP = 136; base = WD128_U16; e -= 7680; }
        int m = e / NP, t = e % NP;
        float v = 0.f;
        if (t < N && m < N + 2) {
            float ang = 6.2831853071795864769f * (float)(((m >> 1) * t) & (N - 1)) / (float)N;
            v = (m & 1) ? -sinf(ang) : cosf(ang);
        }
        ((unsigned short*)(ws + WD_OFF))[base + e] = (unsigned short)f2bf(v);
        return;
    }
    e -= WD_ELEMS;
    if (e < WA_ELEMS) {
        int N, S3, base;
        if (e < 2304)      { N = 32;  S3 = 72;  base = 0; }
        else if (e < 8960) { N = 64;  S3 = 104; base = WA64_U16;  e -= 2304; }
        else               { N = 128; S3 = 168; base = WA128_U16; e -= 8960; }
        int t = e / S3, kk = e % S3;
        int BINS = N / 2 + 1;
        float v = 0.f;
        if (kk < BINS)
            v = cosf(6.2831853071795864769f * (float)((kk * t) & (N - 1)) / (float)N);
        else if (kk < N + 2)
            v = -sinf(6.2831853071795864769f * (float)(((kk - BINS) * t) & (N - 1)) / (float)N);
        ((unsigned short*)(ws + WA_OFF))[base + e] = (unsigned short)f2bf(v);
    }
}

// weights-only prep for the small-ws fused fallback
__global__ void prep_resize(const float* __restrict__ kr, const float* __restrict__ ki,
                            uint32_t* __restrict__ wsu)
{
    int idx = blockIdx.x * 256 + threadIdx.x;
    if (idx >= WS_TOTAL_PAIRS) return;
    int bins, rem = idx;
    if (rem < 17 * 2048)      { bins = 17; }
    else if (rem < 50 * 2048) { bins = 33; rem -= 17 * 2048; }
    else                      { bins = 65; rem -= 50 * 2048; }
    int k = rem >> 11, co = rem & 2047;
    float s  = (k + 0.5f) * (33.0f / bins) - 0.5f;
    float fl = floorf(s);
    float w1 = s - fl;
    int i0 = min(max((int)fl, 0), 32);
    int i1 = min(max((int)fl + 1, 0), 32);
    float r0 = kr[i0 * 2048 + co], r1 = kr[i1 * 2048 + co];
    float q0 = ki[i0 * 2048 + co], q1 = ki[i1 * 2048 + co];
    wsu[idx] = pk2(fmaf(w1, r1 - r0, r0), fmaf(w1, q1 - q0, q0));
}

// ================= MFMA fragment loader (row-major LDS, k contiguous) ==========
__device__ __forceinline__ s8v ldfr(const unsigned short* p, int stride, int row0, int k0){
    int lane = threadIdx.x & 63;
    return *(const s8v*)(p + (row0 + (lane & 15)) * stride + k0 + ((lane >> 4) << 3));
}

// ================= K1W: all 3 branches' DFT from one 128-sample x tile =========
template<int N, int NTW>
__device__ __forceinline__ void k1w_branch(const unsigned short* __restrict__ W,
        const unsigned short* __restrict__ xT, uint32_t* __restrict__ xfp, int b, int w)
{
    constexpr int BINS = N/2+1, M2 = 2*BINS, MPAD = ((M2+15)/16)*16;
    constexpr int MT = MPAD/16, KS = N/32, NP = N+8;
    constexpr int F = 128/N, FRAMES = 8192/N, BF = 8*FRAMES;
    const int tid = threadIdx.x, wv = tid >> 6, lane = tid & 63;
    const int nt0 = wv * NTW, cl = lane & 15, kl = (lane >> 4) << 3, rg = (lane >> 4) * 4;

    f4v acc[MT][NTW];
    #pragma unroll
    for (int mt = 0; mt < MT; ++mt)
        #pragma unroll
        for (int nw = 0; nw < NTW; ++nw) { f4v zz = {0.f,0.f,0.f,0.f}; acc[mt][nw] = zz; }

    for (int ks = 0; ks < KS; ++ks) {
        s8v a[MT];
        #pragma unroll
        for (int mt = 0; mt < MT; ++mt) a[mt] = ldfr(W, NP, mt*16, ks*32);
        #pragma unroll
        for (int nw = 0; nw < NTW; ++nw) {
            int rowb = (nt0+nw)*16 + cl;
            s8v bb = *(const s8v*)(xT + (rowb & 63)*136 + (rowb >> 6)*N + ks*32 + kl);
            #pragma unroll
            for (int mt = 0; mt < MT; ++mt)
                acc[mt][nw] = __builtin_amdgcn_mfma_f32_16x16x32_bf16(a[mt], bb, acc[mt][nw], 0, 0, 0);
        }
    }
    #pragma unroll
    for (int mt = 0; mt < MT; ++mt)
      #pragma unroll
      for (int nw = 0; nw < NTW; ++nw) {
        int col = (nt0+nw)*16 + cl, f = col >> 6, c = col & 63;
        size_t bf = (size_t)b*FRAMES + w*F + f;
        #pragma unroll
        for (int r = 0; r < 4; r += 2) {
            int m = mt*16 + rg + r, k = m >> 1;
            if (k < BINS)
                xfp[((size_t)k*BF + bf)*64 + c] = pk2(acc[mt][nw][r], acc[mt][nw][r+1]);
        }
      }
}

__global__ __launch_bounds__(256, 2) void k1w(const float* __restrict__ x, char* __restrict__ ws)
{
    __shared__ __align__(16) char smem[71936];
    unsigned short* xT   = (unsigned short*)smem;        // [64 c][136], t in [0,128)
    unsigned short* Wall = xT + 64*136;                  // W32|W64|W128 (27264 u16)
    const unsigned short* WD = (const unsigned short*)(ws + WD_OFF);
    const int tid = threadIdx.x, bid = blockIdx.x;
    const int b = bid >> 6, w = bid & 63;

    for (int e = tid; e < WD_ELEMS/8; e += 256)
        *(uint4*)(Wall + e*8) = *(const uint4*)(WD + e*8);

    const float* xb = x + ((size_t)b*T_SZ + (size_t)w*128) * 64;
    for (int e = tid; e < 512; e += 256) {
        int c4 = e & 15, t0 = (e >> 4) * 4;
        const float* p = xb + (size_t)t0*64 + c4*4;
        float4 v0 = *(const float4*)(p);
        float4 v1 = *(const float4*)(p + 64);
        float4 v2 = *(const float4*)(p + 128);
        float4 v3 = *(const float4*)(p + 192);
        unsigned short* d = xT + (c4*4)*136 + t0;
        *(uint2*)(d)       = make_uint2(pk2(v0.x, v1.x), pk2(v2.x, v3.x));
        *(uint2*)(d + 136) = make_uint2(pk2(v0.y, v1.y), pk2(v2.y, v3.y));
        *(uint2*)(d + 272) = make_uint2(pk2(v0.z, v1.z), pk2(v2.z, v3.z));
        *(uint2*)(d + 408) = make_uint2(pk2(v0.w, v1.w), pk2(v2.w, v3.w));
    }
    __syncthreads();

    k1w_branch<32, 4>(Wall,             xT, (uint32_t*)(ws + XF32W),  b, w);
    k1w_branch<64, 2>(Wall + WD64_U16,  xT, (uint32_t*)(ws + XF64W),  b, w);
    k1w_branch<128,1>(Wall + WD128_U16, xT, (uint32_t*)(ws + XF128W), b, w);
}

// ================= K2: per-bin complex mix + leaky (wk pre-folded) =============
template<int N>
__device__ __forceinline__ void k2_body(int kbin, int mblk, char* smem,
        const unsigned short* __restrict__ we, const uint32_t* __restrict__ xfp,
        unsigned short* __restrict__ y2)
{
    constexpr int BINS = N/2+1, FRAMES = 8192/N, BF = 8*FRAMES, M2 = 2*BINS;
    constexpr int GOFF = (N==32) ? 0 : (N==64) ? 17 : 50;
    unsigned short* A  = (unsigned short*)smem;   // [128 bf][136] paired {c0R,c0I,...}
    unsigned short* W2 = A + 128*136;             // [64 outcol][136]
    const int tid = threadIdx.x;
    const int bf0 = mblk * 128;

    for (int e = tid; e < 2048; e += 256)
        *(uint4*)(A + (e>>4)*136 + (e&15)*8) =
            *((const uint4*)(xfp + ((size_t)kbin*BF + bf0 + (e>>4))*64) + (e & 15));

    const uint4* wsrc = (const uint4*)(we + (size_t)(GOFF + kbin) * 8192);
    for (int e = tid; e < 1024; e += 256)
        *(uint4*)(W2 + (e>>4)*136 + (e&15)*8) = wsrc[e];
    __syncthreads();

    const int wv = tid >> 6, lane = tid & 63;
    const int mt0 = wv * 2;
    f4v acc[2][4];
    #pragma unroll
    for (int mt = 0; mt < 2; ++mt)
        #pragma unroll
        for (int nt = 0; nt < 4; ++nt) { f4v zz = {0.f,0.f,0.f,0.f}; acc[mt][nt] = zz; }

    for (int ks = 0; ks < 4; ++ks) {
        s8v a0 = ldfr(A, 136, mt0*16, ks*32);
        s8v a1 = ldfr(A, 136, mt0*16 + 16, ks*32);
        #pragma unroll
        for (int nt = 0; nt < 4; ++nt) {
            s8v bb = ldfr(W2, 136, nt*16, ks*32);
            acc[0][nt] = __builtin_amdgcn_mfma_f32_16x16x32_bf16(a0, bb, acc[0][nt], 0, 0, 0);
            acc[1][nt] = __builtin_amdgcn_mfma_f32_16x16x32_bf16(a1, bb, acc[1][nt], 0, 0, 0);
        }
    }
    const int cl = lane & 15, rg = (lane >> 4) * 4;
    #pragma unroll
    for (int mt = 0; mt < 2; ++mt)
      #pragma unroll
      for (int nt = 0; nt < 4; ++nt) {
        int col = nt*16 + cl;
        int kk = (col < 32) ? kbin : BINS + kbin;
        int o = col & 31;
        #pragma unroll
        for (int r = 0; r < 4; ++r) {
            int bf = bf0 + (mt0+mt)*16 + rg + r;
            float v = acc[mt][nt][r];
            v = (v > 0.f) ? v : 0.2f * v;
            y2[((size_t)bf*M2 + kk)*32 + o] = (unsigned short)f2bf(v);
        }
      }
}

__global__ __launch_bounds__(256, 3) void k2all(char* __restrict__ ws)
{
    __shared__ __align__(16) char smem[52224];
    const unsigned short* we = (const unsigned short*)(ws + WE_OFF);
    int bid = blockIdx.x;
    if (bid < 272)
        k2_body<32>(bid >> 4, bid & 15, smem, we,
                    (const uint32_t*)(ws + XF32W), (unsigned short*)(ws + Y32W));
    else if (bid < 536) {
        int q = bid - 272;
        k2_body<64>(q >> 3, q & 7, smem, we,
                    (const uint32_t*)(ws + XF64W), (unsigned short*)(ws + Y64W));
    } else {
        int q = bid - 536;
        k2_body<128>(q >> 2, q & 3, smem, we,
                     (const uint32_t*)(ws + XF128W), (unsigned short*)(ws + Y128W));
    }
}

// ================= K3: iDFT + bias =============================================
template<int N, int TROWS>
__device__ __forceinline__ void k3_body(int b, int f0, int t0, char* smem,
        const unsigned short* __restrict__ WA, const unsigned short* __restrict__ y2,
        const float* __restrict__ bias, float* __restrict__ out)
{
    constexpr int BINS = N/2+1, FRAMES = 8192/N, M2 = 2*BINS;
    constexpr int KP = ((M2+31)/32)*32, S3 = KP+8, KS = KP/32;
    constexpr int FB = (N==32)?8:(N==64)?4:2;
    constexpr int COFF = (N==32)?0:(N==64)?32:64;
    constexpr int NTW = (N==128)?4:8;

    unsigned short* A  = (unsigned short*)smem;   // [TROWS][S3] (zeros beyond M2)
    unsigned short* Bt = A + TROWS*S3;            // [FB*32][S3]
    const int tid = threadIdx.x;

    for (int e = tid; e < TROWS*S3/8; e += 256)
        *(uint4*)(A + e*8) = *(const uint4*)(WA + t0*S3 + e*8);

    for (int e = tid; e < FB*M2*4; e += 256) {
        int f = e / (M2*4), r = e % (M2*4), kk = r >> 2, og = (r & 3)*8;
        size_t bf = (size_t)b*FRAMES + f0 + f;
        uint4 v = *((const uint4*)(y2 + ((size_t)bf*M2 + kk)*32) + (r & 3));
        unsigned short* dst = Bt + (f*32 + og)*S3 + kk;
        const unsigned short* pv = (const unsigned short*)&v;
        #pragma unroll
        for (int j = 0; j < 8; ++j) dst[j*S3] = pv[j];
    }
    __syncthreads();

    const int wv = tid >> 6, lane = tid & 63;
    const int mt0 = (N==32) ? (wv & 1) : wv;
    const int nt0 = (N==32) ? (wv >> 1)*8 : 0;

    f4v acc[NTW];
    #pragma unroll
    for (int nw = 0; nw < NTW; ++nw) { f4v zz = {0.f,0.f,0.f,0.f}; acc[nw] = zz; }

    for (int ks = 0; ks < KS; ++ks) {
        s8v a = ldfr(A, S3, mt0*16, ks*32);
        #pragma unroll
        for (int nw = 0; nw < NTW; ++nw) {
            s8v bb = ldfr(Bt, S3, (nt0+nw)*16, ks*32);
            acc[nw] = __builtin_amdgcn_mfma_f32_16x16x32_bf16(a, bb, acc[nw], 0, 0, 0);
        }
    }
    const int cl = lane & 15, rg = (lane >> 4) * 4;
    #pragma unroll
    for (int nw = 0; nw < NTW; ++nw) {
        int col = (nt0+nw)*16 + cl, f = col >> 5, o = col & 31;
        float bv = bias[COFF + o];
        #pragma unroll
        for (int r = 0; r < 4; ++r) {
            int t = t0 + mt0*16 + rg + r;
            out[((size_t)(b*T_SZ + (f0+f)*N + t))*NCH + COFF + o] = acc[nw][r] + bv;
        }
    }
}

__global__ __launch_bounds__(256, 3) void k3all(char* __restrict__ ws,
        const float* __restrict__ bias, float* __restrict__ out)
{
    __shared__ __align__(16) char smem[43008];
    const unsigned short* WA = (const unsigned short*)(ws + WA_OFF);
    int bid = blockIdx.x;
    if (bid < 256)
        k3_body<32,32>(bid >> 5, (bid & 31)*8, 0, smem, WA,
                       (const unsigned short*)(ws + Y32W), bias, out);
    else if (bid < 512) {
        int q = bid - 256;
        k3_body<64,64>(q >> 5, (q & 31)*4, 0, smem, WA + WA64_U16,
                       (const unsigned short*)(ws + Y64W), bias, out);
    } else {
        int q = bid - 512;
        k3_body<128,64>(q >> 6, ((q & 63) >> 1)*2, (q & 1)*64, smem, WA + WA128_U16,
                        (const unsigned short*)(ws + Y128W), bias, out);
    }
}

// ======================= fallback: round-1 fused VALU path =====================
template<int FFT_N, bool USE_WS>
__global__ __launch_bounds__(256, 2)
void stft_fused(const float* __restrict__ x, const float* __restrict__ kr,
                const float* __restrict__ ki, const float* __restrict__ bias,
                const uint32_t* __restrict__ wsu, float* __restrict__ out)
{
    constexpr int CIN = 64, COUT = 32;
    constexpr int BINS = FFT_N / 2 + 1;
    constexpr int NFR  = 128 / FFT_N;
    constexpr int KQ   = (BINS + 3) / 4;
    constexpr int COFF = (FFT_N == 32) ? 0 : (FFT_N == 64) ? 32 : 64;
    constexpr int WSP  = (FFT_N == 32) ? 0 : (FFT_N == 64) ? 17 * 2048 : 50 * 2048;
    constexpr int XSP  = 68;
    constexpr int CP   = 66;
    constexpr int YP   = BINS + 2;
    constexpr int SMEMF = 128 * XSP + 2 * FFT_N + NFR * BINS * CP * 2;

    __shared__ __align__(16) float smem[SMEMF];
    float*  xs  = smem;
    float2* cst = (float2*)(smem + 128 * XSP);
    float2* xf2 = (float2*)(smem + 128 * XSP + 2 * FFT_N);
    float2* Y2  = (float2*)smem;

    const int tid = threadIdx.x;
    const int bid = blockIdx.x;
    const int b = bid >> 6, w = bid & 63;
    const float* xblk = x + (size_t)(b * T_SZ + w * 128) * CIN;

    for (int i = tid; i < 2048; i += 256) {
        float4 v = ((const float4*)xblk)[i];
        int t = i >> 4;
        int c = (i & 15) * 4;
        *(float4*)&xs[t * XSP + c] = v;
    }
    if (tid < FFT_N) {
        float ang = 6.2831853071795864769f * ((float)tid / (float)FFT_N);
        float sv, cv;
        sincosf(ang, &sv, &cv);
        cst[tid] = make_float2(cv, sv);
    }
    __syncthreads();

    constexpr int NT_DFT = NFR * KQ * 16;
    for (int tile = tid; tile < NT_DFT; tile += 256) {
        int cq  = tile & 15;
        int kqf = tile >> 4;
        int kq  = kqf % KQ, f = kqf / KQ;
        int k0  = kq * 4;
        float accr[4][4] = {};
        float acci[4][4] = {};
        int idx[4] = {0, 0, 0, 0};
        const float* xrow = xs + f * FFT_N * XSP + cq * 4;
        for (int t = 0; t < FFT_N; ++t) {
            float4 xv = *(const float4*)(xrow + t * XSP);
            float xc[4] = {xv.x, xv.y, xv.z, xv.w};
            #pragma unroll
            for (int kk = 0; kk < 4; ++kk) {
                float2 tw = cst[idx[kk]];
                idx[kk] = (idx[kk] + k0 + kk) & (FFT_N - 1);
                #pragma unroll
                for (int cc = 0; cc < 4; ++cc) {
                    accr[kk][cc] = fmaf(xc[cc], tw.x, accr[kk][cc]);
                    acci[kk][cc] = fmaf(xc[cc], tw.y, acci[kk][cc]);
                }
            }
        }
        #pragma unroll
        for (int kk = 0; kk < 4; ++kk) {
            int k = k0 + kk;
            if (k < BINS) {
                #pragma unroll
                for (int cc = 0; cc < 4; ++cc)
                    xf2[(f * BINS + k) * CP + cq * 4 + cc] =
                        make_float2(accr[kk][cc], -acci[kk][cc]);
            }
        }
    }
    __syncthreads();

    constexpr int NT_MM = BINS * 8;
    for (int task = tid; task < NT_MM; task += 256) {
        int oq = task & 7, k = task >> 3;
        float2 accY[NFR][4] = {};
        float w1 = 0.f; int i0 = 0, i1 = 0;
        if (!USE_WS) {
            float s  = (k + 0.5f) * (33.0f / BINS) - 0.5f;
            float fl = floorf(s); w1 = s - fl;
            i0 = min(max((int)fl, 0), 32);
            i1 = min(max((int)fl + 1, 0), 32);
        }
        const uint32_t* wp = USE_WS ? (wsu + WSP + k * 2048 + oq * 4) : (const uint32_t*)nullptr;
        for (int c = 0; c < CIN; ++c) {
            float krv[4], kiv[4];
            if (USE_WS) {
                uint4 u = *(const uint4*)(wp + c * 32);
                krv[0] = lo_bf(u.x); kiv[0] = hi_bf(u.x);
                krv[1] = lo_bf(u.y); kiv[1] = hi_bf(u.y);
                krv[2] = lo_bf(u.z); kiv[2] = hi_bf(u.z);
                krv[3] = lo_bf(u.w); kiv[3] = hi_bf(u.w);
            } else {
                const float* p = kr + (size_t)i0 * 2048 + c * 32 + oq * 4;
                const float* q = kr + (size_t)i1 * 2048 + c * 32 + oq * 4;
                float4 r0 = *(const float4*)p, r1 = *(const float4*)q;
                p = ki + (size_t)i0 * 2048 + c * 32 + oq * 4;
                q = ki + (size_t)i1 * 2048 + c * 32 + oq * 4;
                float4 q0 = *(const float4*)p, q1 = *(const float4*)q;
                krv[0] = fmaf(w1, r1.x - r0.x, r0.x); kiv[0] = fmaf(w1, q1.x - q0.x, q0.x);
                krv[1] = fmaf(w1, r1.y - r0.y, r0.y); kiv[1] = fmaf(w1, q1.y - q0.y, q0.y);
                krv[2] = fmaf(w1, r1.z - r0.z, r0.z); kiv[2] = fmaf(w1, q1.z - q0.z, q0.z);
                krv[3] = fmaf(w1, r1.w - r0.w, r0.w); kiv[3] = fmaf(w1, q1.w - q0.w, q0.w);
            }
            #pragma unroll
            for (int f = 0; f < NFR; ++f) {
                float2 xv = xf2[(f * BINS + k) * CP + c];
                #pragma unroll
                for (int jo = 0; jo < 4; ++jo) {
                    accY[f][jo].x += xv.x * krv[jo] - xv.y * kiv[jo];
                    accY[f][jo].y += xv.x * kiv[jo] + xv.y * krv[jo];
                }
            }
        }
        float wk = (k == 0 || k == BINS - 1) ? (1.0f / FFT_N) : (2.0f / FFT_N);
        #pragma unroll
        for (int f = 0; f < NFR; ++f) {
            #pragma unroll
            for (int jo = 0; jo < 4; ++jo) {
                float yr = accY[f][jo].x; yr = (yr > 0.f) ? yr : 0.2f * yr;
                float yi = accY[f][jo].y; yi = (yi > 0.f) ? yi : 0.2f * yi;
                Y2[(f * COUT + oq * 4 + jo) * YP + k] = make_float2(yr * wk, yi * wk);
            }
        }
    }
    __syncthreads();

    {
        int tq = tid >> 3, oq = tid & 7;
        int tg0 = tq * 4;
        int f   = tg0 / FFT_N;
        int tl0 = tg0 % FFT_N;
        float acc[4][4] = {};
        int idx[4] = {0, 0, 0, 0};
        const float2* yb = Y2 + (f * COUT + oq * 4) * YP;
        for (int k = 0; k < BINS; ++k) {
            float2 tw[4];
            #pragma unroll
            for (int j = 0; j < 4; ++j) {
                tw[j] = cst[idx[j]];
                idx[j] = (idx[j] + tl0 + j) & (FFT_N - 1);
            }
            #pragma unroll
            for (int jo = 0; jo < 4; ++jo) {
                float2 yv = yb[jo * YP + k];
                #pragma unroll
                for (int j = 0; j < 4; ++j)
                    acc[j][jo] += yv.x * tw[j].x - yv.y * tw[j].y;
            }
        }
        float4 bv = *(const float4*)(bias + COFF + oq * 4);
        float* ob = out + ((size_t)(b * T_SZ + w * 128 + tg0)) * NCH + COFF + oq * 4;
        #pragma unroll
        for (int j = 0; j < 4; ++j) {
            float4 o4 = make_float4(acc[j][0] + bv.x, acc[j][1] + bv.y,
                                    acc[j][2] + bv.z, acc[j][3] + bv.w);
            *(float4*)(ob + (size_t)j * NCH) = o4;
        }
    }
}

// =============================== launch ========================================
extern "C" void kernel_launch(void* const* d_in, const int* in_sizes, int n_in,
                              void* d_out, int out_size, void* d_ws, size_t ws_size,
                              hipStream_t stream)
{
    (void)in_sizes; (void)n_in; (void)out_size;
    const float* x    = (const float*)d_in[0];
    const float* kr   = (const float*)d_in[1];
    const float* ki   = (const float*)d_in[2];
    const float* bias = (const float*)d_in[3];
    float* out = (float*)d_out;
    char* ws = (char*)d_ws;
    dim3 blk(256);

    if (ws != nullptr && ws_size >= (size_t)WS_WIDE) {
        prep_full<<<dim3(2066), blk, 0, stream>>>(kr, ki, ws);
        k1w   <<<dim3(512),  blk, 0, stream>>>(x, ws);
        k2all <<<dim3(796),  blk, 0, stream>>>(ws);
        k3all <<<dim3(1024), blk, 0, stream>>>(ws, bias, out);
    } else if (ws != nullptr && ws_size >= (size_t)WS_TOTAL_PAIRS * 4) {
        uint32_t* wsu = (uint32_t*)ws;
        prep_resize<<<dim3(920), blk, 0, stream>>>(kr, ki, wsu);
        stft_fused<32,  true><<<dim3(512), blk, 0, stream>>>(x, kr, ki, bias, wsu, out);
        stft_fused<64,  true><<<dim3(512), blk, 0, stream>>>(x, kr, ki, bias, wsu, out);
        stft_fused<128, true><<<dim3(512), blk, 0, stream>>>(x, kr, ki, bias, wsu, out);
    } else {
        stft_fused<32,  false><<<dim3(512), blk, 0, stream>>>(x, kr, ki, bias, nullptr, out);
        stft_fused<64,  false><<<dim3(512), blk, 0, stream>>>(x, kr, ki, bias, nullptr, out);
        stft_fused<128, false><<<dim3(512), blk, 0, stream>>>(x, kr, ki, bias, nullptr, out);
    }
}

// Round 6
// 48.135 us; speedup vs baseline: 1.0465x; 1.0465x over previous
//
#include <hip/hip_runtime.h>
#include <stdint.h>

#define T_SZ 8192
#define NCH 96

typedef __attribute__((ext_vector_type(8))) short s8v;
typedef __attribute__((ext_vector_type(4))) float f4v;

// ---------- bf16 helpers ----------
__device__ __forceinline__ float lo_bf(uint32_t u){ return __uint_as_float(u << 16); }
__device__ __forceinline__ float hi_bf(uint32_t u){ return __uint_as_float(u & 0xffff0000u); }
__device__ __forceinline__ uint32_t f2bf(float f){
    uint32_t u = __float_as_uint(f);
    return (u + 0x7fffu + ((u >> 16) & 1u)) >> 16;   // RNE
}
__device__ __forceinline__ uint32_t pk2(float a, float b){ return f2bf(a) | (f2bf(b) << 16); }

// ---------- ws layout (bytes) ----------
#define WS_TOTAL_PAIRS 235520          // fused-fallback packed pairs
#define WD_OFF    942080               // DFT matrices W32[48][40] W64[80][72] W128[144][136]
#define WD_ELEMS  27264
#define WA_OFF    996608               // iDFT matrices A32[32][72] A64[64][104] A128[128][168]
#define WA_ELEMS  30464                //   (kk interleaved: 2k=cos, 2k+1=-sin)
#define WD64_U16   1920
#define WD128_U16  7680
#define WA64_U16   2304
#define WA128_U16  8960
// wide-path scratch regions
#define XF32W    4194304
#define XF64W   14680064
#define XF128W  25165824
#define Y32W    35651584               // y2 paired u32 [bf][k][o]
#define Y64W    41943040
#define Y128W   50331648
#define WS_WIDE 58720256

// ================= prep: DFT/iDFT coefficient matrices ========================
__global__ void prep_full(char* __restrict__ ws)
{
    int e = blockIdx.x * 256 + threadIdx.x;
    if (e < WD_ELEMS) {
        int N, NP, base;
        if (e < 1920)      { N = 32;  NP = 40;  base = 0; }
        else if (e < 7680) { N = 64;  NP = 72;  base = WD64_U16;  e -= 1920; }
        else               { N = 128; NP = 136; base = WD128_U16; e -= 7680; }
        int m = e / NP, t = e % NP;
        float v = 0.f;
        if (t < N && m < N + 2) {
            float ang = 6.2831853071795864769f * (float)(((m >> 1) * t) & (N - 1)) / (float)N;
            v = (m & 1) ? -sinf(ang) : cosf(ang);
        }
        ((unsigned short*)(ws + WD_OFF))[base + e] = (unsigned short)f2bf(v);
        return;
    }
    e -= WD_ELEMS;
    if (e < WA_ELEMS) {
        int N, S3, base;
        if (e < 2304)      { N = 32;  S3 = 72;  base = 0; }
        else if (e < 8960) { N = 64;  S3 = 104; base = WA64_U16;  e -= 2304; }
        else               { N = 128; S3 = 168; base = WA128_U16; e -= 8960; }
        int t = e / S3, kk = e % S3;
        int M2 = N + 2;
        float v = 0.f;
        if (kk < M2) {
            int k = kk >> 1;
            float ang = 6.2831853071795864769f * (float)((k * t) & (N - 1)) / (float)N;
            v = (kk & 1) ? -sinf(ang) : cosf(ang);
        }
        ((unsigned short*)(ws + WA_OFF))[base + e] = (unsigned short)f2bf(v);
    }
}

// weights-only prep for the small-ws fused fallback
__global__ void prep_resize(const float* __restrict__ kr, const float* __restrict__ ki,
                            uint32_t* __restrict__ wsu)
{
    int idx = blockIdx.x * 256 + threadIdx.x;
    if (idx >= WS_TOTAL_PAIRS) return;
    int bins, rem = idx;
    if (rem < 17 * 2048)      { bins = 17; }
    else if (rem < 50 * 2048) { bins = 33; rem -= 17 * 2048; }
    else                      { bins = 65; rem -= 50 * 2048; }
    int k = rem >> 11, co = rem & 2047;
    float s  = (k + 0.5f) * (33.0f / bins) - 0.5f;
    float fl = floorf(s);
    float w1 = s - fl;
    int i0 = min(max((int)fl, 0), 32);
    int i1 = min(max((int)fl + 1, 0), 32);
    float r0 = kr[i0 * 2048 + co], r1 = kr[i1 * 2048 + co];
    float q0 = ki[i0 * 2048 + co], q1 = ki[i1 * 2048 + co];
    wsu[idx] = pk2(fmaf(w1, r1 - r0, r0), fmaf(w1, q1 - q0, q0));
}

// ================= MFMA fragment loader (row-major LDS, k contiguous) ==========
__device__ __forceinline__ s8v ldfr(const unsigned short* p, int stride, int row0, int k0){
    int lane = threadIdx.x & 63;
    return *(const s8v*)(p + (row0 + (lane & 15)) * stride + k0 + ((lane >> 4) << 3));
}

// ================= K1W: all 3 branches' DFT from one 128-sample x tile =========
// 512-thread blocks (8 waves); each branch's col-tiles split across 8 waves.
template<int N, int NTW, int MT0, int MTN>
__device__ __forceinline__ void k1w_branch(const unsigned short* __restrict__ W,
        const unsigned short* __restrict__ xT, uint32_t* __restrict__ xfp,
        int b, int w, int nt0)
{
    constexpr int BINS = N/2+1, KS = N/32, NP = N+8;
    constexpr int F = 128/N, FRAMES = 8192/N;
    const int lane = threadIdx.x & 63;
    const int cl = lane & 15, kl = (lane >> 4) << 3, rg = (lane >> 4) * 4;

    f4v acc[MTN][NTW];
    #pragma unroll
    for (int mt = 0; mt < MTN; ++mt)
        #pragma unroll
        for (int nw = 0; nw < NTW; ++nw) { f4v zz = {0.f,0.f,0.f,0.f}; acc[mt][nw] = zz; }

    for (int ks = 0; ks < KS; ++ks) {
        s8v a[MTN];
        #pragma unroll
        for (int mt = 0; mt < MTN; ++mt) a[mt] = ldfr(W, NP, (MT0+mt)*16, ks*32);
        #pragma unroll
        for (int nw = 0; nw < NTW; ++nw) {
            int rowb = (nt0+nw)*16 + cl;
            s8v bb = *(const s8v*)(xT + (rowb & 63)*136 + (rowb >> 6)*N + ks*32 + kl);
            #pragma unroll
            for (int mt = 0; mt < MTN; ++mt)
                acc[mt][nw] = __builtin_amdgcn_mfma_f32_16x16x32_bf16(a[mt], bb, acc[mt][nw], 0, 0, 0);
        }
    }
    #pragma unroll
    for (int mt = 0; mt < MTN; ++mt)
      #pragma unroll
      for (int nw = 0; nw < NTW; ++nw) {
        int col = (nt0+nw)*16 + cl, f = col >> 6, c = col & 63;
        size_t bf = (size_t)b*FRAMES + w*F + f;
        #pragma unroll
        for (int r = 0; r < 4; r += 2) {
            int m = (MT0+mt)*16 + rg + r, k = m >> 1;
            if (k < BINS)
                xfp[((size_t)k*(8*FRAMES) + bf)*64 + c] = pk2(acc[mt][nw][r], acc[mt][nw][r+1]);
        }
      }
}

__global__ __launch_bounds__(512, 4) void k1w(const float* __restrict__ x, char* __restrict__ ws)
{
    __shared__ __align__(16) char smem[71936];
    unsigned short* xT   = (unsigned short*)smem;        // [64 c][136], t in [0,128)
    unsigned short* Wall = xT + 64*136;                  // W32|W64|W128 (27264 u16)
    const unsigned short* WD = (const unsigned short*)(ws + WD_OFF);
    const int tid = threadIdx.x, bid = blockIdx.x;
    const int b = bid >> 6, w = bid & 63;

    for (int e = tid; e < WD_ELEMS/8; e += 512)
        *(uint4*)(Wall + e*8) = *(const uint4*)(WD + e*8);

    const float* xb = x + ((size_t)b*T_SZ + (size_t)w*128) * 64;
    {
        int e = tid;                                     // 512 tasks, 1 each
        int c4 = e & 15, t0 = (e >> 4) * 4;
        const float* p = xb + (size_t)t0*64 + c4*4;
        float4 v0 = *(const float4*)(p);
        float4 v1 = *(const float4*)(p + 64);
        float4 v2 = *(const float4*)(p + 128);
        float4 v3 = *(const float4*)(p + 192);
        unsigned short* d = xT + (c4*4)*136 + t0;
        *(uint2*)(d)       = make_uint2(pk2(v0.x, v1.x), pk2(v2.x, v3.x));
        *(uint2*)(d + 136) = make_uint2(pk2(v0.y, v1.y), pk2(v2.y, v3.y));
        *(uint2*)(d + 272) = make_uint2(pk2(v0.z, v1.z), pk2(v2.z, v3.z));
        *(uint2*)(d + 408) = make_uint2(pk2(v0.w, v1.w), pk2(v2.w, v3.w));
    }
    __syncthreads();

    const int wv = tid >> 6;
    // branch32: COLS=256 -> 16 col-tiles, 8 waves x NTW=2 ; MPAD=48 -> MT=3
    k1w_branch<32, 2, 0, 3>(Wall,             xT, (uint32_t*)(ws + XF32W),  b, w, wv*2);
    // branch64: COLS=128 -> 8 col-tiles, 8 waves x NTW=1 ; MPAD=80 -> MT=5
    k1w_branch<64, 1, 0, 5>(Wall + WD64_U16,  xT, (uint32_t*)(ws + XF64W),  b, w, wv);
    // branch128: COLS=64 -> 4 col-tiles; waves 0-3 m-tiles 0..4, waves 4-7 m-tiles 5..8
    if (wv < 4)
        k1w_branch<128, 1, 0, 5>(Wall + WD128_U16, xT, (uint32_t*)(ws + XF128W), b, w, wv);
    else
        k1w_branch<128, 1, 5, 4>(Wall + WD128_U16, xT, (uint32_t*)(ws + XF128W), b, w, wv & 3);
}

// ================= K2: per-bin complex mix + leaky (W2 from kr/ki, wk folded) ==
template<int N>
__device__ __forceinline__ void k2_body(int kbin, int mblk, char* smem,
        const float* __restrict__ kr, const float* __restrict__ ki,
        const uint32_t* __restrict__ xfp, uint32_t* __restrict__ y2p)
{
    constexpr int BINS = N/2+1, FRAMES = 8192/N, BF = 8*FRAMES;
    unsigned short* A  = (unsigned short*)smem;   // [128 bf][136] paired {c0R,c0I,...}
    unsigned short* W2 = A + 128*136;             // [64 outcol][136]
    const int tid = threadIdx.x;
    const int bf0 = mblk * 128;

    for (int e = tid; e < 2048; e += 256)
        *(uint4*)(A + (e>>4)*136 + (e&15)*8) =
            *((const uint4*)(xfp + ((size_t)kbin*BF + bf0 + (e>>4))*64) + (e & 15));

    {   // build W2 straight from kr/ki (coalesced 8KB rows, L3-hot)
        float s  = (kbin + 0.5f) * (33.0f / BINS) - 0.5f;
        float fl = floorf(s);
        float w1 = s - fl;
        int i0 = min(max((int)fl, 0), 32);
        int i1 = min(max((int)fl + 1, 0), 32);
        float wk = (kbin == 0 || kbin == BINS-1) ? (1.0f/N) : (2.0f/N);  // pow2: exact
        for (int e = tid; e < 2048; e += 256) {
            float r0 = kr[i0*2048 + e], r1 = kr[i1*2048 + e];
            float q0 = ki[i0*2048 + e], q1 = ki[i1*2048 + e];
            float vr = fmaf(w1, r1 - r0, r0) * wk;
            float vi = fmaf(w1, q1 - q0, q0) * wk;
            int c = e >> 5, o = e & 31;
            W2[o*136 + 2*c]          = (unsigned short)f2bf(vr);
            W2[o*136 + 2*c + 1]      = (unsigned short)f2bf(-vi);
            W2[(32+o)*136 + 2*c]     = (unsigned short)f2bf(vi);
            W2[(32+o)*136 + 2*c + 1] = (unsigned short)f2bf(vr);
        }
    }
    __syncthreads();

    const int wv = tid >> 6, lane = tid & 63;
    const int mt0 = wv * 2;
    f4v acc[2][4];
    #pragma unroll
    for (int mt = 0; mt < 2; ++mt)
        #pragma unroll
        for (int nt = 0; nt < 4; ++nt) { f4v zz = {0.f,0.f,0.f,0.f}; acc[mt][nt] = zz; }

    for (int ks = 0; ks < 4; ++ks) {
        s8v a0 = ldfr(A, 136, mt0*16, ks*32);
        s8v a1 = ldfr(A, 136, mt0*16 + 16, ks*32);
        #pragma unroll
        for (int nt = 0; nt < 4; ++nt) {
            s8v bb = ldfr(W2, 136, nt*16, ks*32);
            acc[0][nt] = __builtin_amdgcn_mfma_f32_16x16x32_bf16(a0, bb, acc[0][nt], 0, 0, 0);
            acc[1][nt] = __builtin_amdgcn_mfma_f32_16x16x32_bf16(a1, bb, acc[1][nt], 0, 0, 0);
        }
    }
    const int cl = lane & 15, rg = (lane >> 4) * 4;
    #pragma unroll
    for (int mt = 0; mt < 2; ++mt)
      #pragma unroll
      for (int nt = 0; nt < 2; ++nt) {           // cols 0..31 = Re; pair with Im (nt+2)
        int o = nt*16 + cl;
        #pragma unroll
        for (int r = 0; r < 4; ++r) {
            int bf = bf0 + (mt0+mt)*16 + rg + r;
            float re = acc[mt][nt][r];   re = (re > 0.f) ? re : 0.2f * re;
            float im = acc[mt][nt+2][r]; im = (im > 0.f) ? im : 0.2f * im;
            y2p[((size_t)bf*BINS + kbin)*32 + o] = pk2(re, im);
        }
      }
}

__global__ __launch_bounds__(256, 3) void k2all(const float* __restrict__ kr,
        const float* __restrict__ ki, char* __restrict__ ws)
{
    __shared__ __align__(16) char smem[52224];
    int bid = blockIdx.x;
    if (bid < 272)
        k2_body<32>(bid >> 4, bid & 15, smem, kr, ki,
                    (const uint32_t*)(ws + XF32W), (uint32_t*)(ws + Y32W));
    else if (bid < 536) {
        int q = bid - 272;
        k2_body<64>(q >> 3, q & 7, smem, kr, ki,
                    (const uint32_t*)(ws + XF64W), (uint32_t*)(ws + Y64W));
    } else {
        int q = bid - 536;
        k2_body<128>(q >> 2, q & 3, smem, kr, ki,
                     (const uint32_t*)(ws + XF128W), (uint32_t*)(ws + Y128W));
    }
}

// ================= K3: iDFT + bias (kk interleaved) ============================
template<int N, int TROWS>
__device__ __forceinline__ void k3_body(int b, int f0, int t0, char* smem,
        const unsigned short* __restrict__ WA, const uint32_t* __restrict__ y2p,
        const float* __restrict__ bias, float* __restrict__ out)
{
    constexpr int BINS = N/2+1, FRAMES = 8192/N, M2 = 2*BINS;
    constexpr int KP = ((M2+31)/32)*32, S3 = KP+8, KS = KP/32;
    constexpr int FB = (N==32)?8:(N==64)?4:2;
    constexpr int NCOLS = FB*32;
    constexpr int COFF = (N==32)?0:(N==64)?32:64;
    constexpr int NTW = (N==128)?4:8;

    unsigned short* A  = (unsigned short*)smem;   // [TROWS][S3] (zeros beyond M2)
    unsigned short* Bt = A + TROWS*S3;            // [NCOLS][S3]
    const int tid = threadIdx.x;

    for (int e = tid; e < TROWS*S3/8; e += 256)
        *(uint4*)(A + e*8) = *(const uint4*)(WA + t0*S3 + e*8);

    for (int e = tid; e < FB*BINS*32; e += 256) {
        int o = e & 31, k = (e >> 5) % BINS, f = e / (32*BINS);
        size_t bf = (size_t)b*FRAMES + f0 + f;
        uint32_t v = y2p[(bf*BINS + k)*32 + o];
        *(uint32_t*)(Bt + (f*32 + o)*S3 + 2*k) = v;   // (Re,Im) -> kk=2k,2k+1
    }
    for (int e = tid; e < NCOLS*15; e += 256) {       // zero pad cols [M2, KP) = 30 u16
        int row = e / 15, j = e % 15;
        *(uint32_t*)(Bt + row*S3 + M2 + 2*j) = 0u;
    }
    __syncthreads();

    const int wv = tid >> 6, lane = tid & 63;
    const int mt0 = (N==32) ? (wv & 1) : wv;
    const int nt0 = (N==32) ? (wv >> 1)*8 : 0;

    f4v acc[NTW];
    #pragma unroll
    for (int nw = 0; nw < NTW; ++nw) { f4v zz = {0.f,0.f,0.f,0.f}; acc[nw] = zz; }

    for (int ks = 0; ks < KS; ++ks) {
        s8v a = ldfr(A, S3, mt0*16, ks*32);
        #pragma unroll
        for (int nw = 0; nw < NTW; ++nw) {
            s8v bb = ldfr(Bt, S3, (nt0+nw)*16, ks*32);
            acc[nw] = __builtin_amdgcn_mfma_f32_16x16x32_bf16(a, bb, acc[nw], 0, 0, 0);
        }
    }
    const int cl = lane & 15, rg = (lane >> 4) * 4;
    #pragma unroll
    for (int nw = 0; nw < NTW; ++nw) {
        int col = (nt0+nw)*16 + cl, f = col >> 5, o = col & 31;
        float bv = bias[COFF + o];
        #pragma unroll
        for (int r = 0; r < 4; ++r) {
            int t = t0 + mt0*16 + rg + r;
            out[((size_t)(b*T_SZ + (f0+f)*N + t))*NCH + COFF + o] = acc[nw][r] + bv;
        }
    }
}

__global__ __launch_bounds__(256, 3) void k3all(char* __restrict__ ws,
        const float* __restrict__ bias, float* __restrict__ out)
{
    __shared__ __align__(16) char smem[43008];
    const unsigned short* WA = (const unsigned short*)(ws + WA_OFF);
    int bid = blockIdx.x;
    if (bid < 256)
        k3_body<32,32>(bid >> 5, (bid & 31)*8, 0, smem, WA,
                       (const uint32_t*)(ws + Y32W), bias, out);
    else if (bid < 512) {
        int q = bid - 256;
        k3_body<64,64>(q >> 5, (q & 31)*4, 0, smem, WA + WA64_U16,
                       (const uint32_t*)(ws + Y64W), bias, out);
    } else {
        int q = bid - 512;
        k3_body<128,64>(q >> 6, ((q & 63) >> 1)*2, (q & 1)*64, smem, WA + WA128_U16,
                        (const uint32_t*)(ws + Y128W), bias, out);
    }
}

// ======================= fallback: round-1 fused VALU path =====================
template<int FFT_N, bool USE_WS>
__global__ __launch_bounds__(256, 2)
void stft_fused(const float* __restrict__ x, const float* __restrict__ kr,
                const float* __restrict__ ki, const float* __restrict__ bias,
                const uint32_t* __restrict__ wsu, float* __restrict__ out)
{
    constexpr int CIN = 64, COUT = 32;
    constexpr int BINS = FFT_N / 2 + 1;
    constexpr int NFR  = 128 / FFT_N;
    constexpr int KQ   = (BINS + 3) / 4;
    constexpr int COFF = (FFT_N == 32) ? 0 : (FFT_N == 64) ? 32 : 64;
    constexpr int WSP  = (FFT_N == 32) ? 0 : (FFT_N == 64) ? 17 * 2048 : 50 * 2048;
    constexpr int XSP  = 68;
    constexpr int CP   = 66;
    constexpr int YP   = BINS + 2;
    constexpr int SMEMF = 128 * XSP + 2 * FFT_N + NFR * BINS * CP * 2;

    __shared__ __align__(16) float smem[SMEMF];
    float*  xs  = smem;
    float2* cst = (float2*)(smem + 128 * XSP);
    float2* xf2 = (float2*)(smem + 128 * XSP + 2 * FFT_N);
    float2* Y2  = (float2*)smem;

    const int tid = threadIdx.x;
    const int bid = blockIdx.x;
    const int b = bid >> 6, w = bid & 63;
    const float* xblk = x + (size_t)(b * T_SZ + w * 128) * CIN;

    for (int i = tid; i < 2048; i += 256) {
        float4 v = ((const float4*)xblk)[i];
        int t = i >> 4;
        int c = (i & 15) * 4;
        *(float4*)&xs[t * XSP + c] = v;
    }
    if (tid < FFT_N) {
        float ang = 6.2831853071795864769f * ((float)tid / (float)FFT_N);
        float sv, cv;
        sincosf(ang, &sv, &cv);
        cst[tid] = make_float2(cv, sv);
    }
    __syncthreads();

    constexpr int NT_DFT = NFR * KQ * 16;
    for (int tile = tid; tile < NT_DFT; tile += 256) {
        int cq  = tile & 15;
        int kqf = tile >> 4;
        int kq  = kqf % KQ, f = kqf / KQ;
        int k0  = kq * 4;
        float accr[4][4] = {};
        float acci[4][4] = {};
        int idx[4] = {0, 0, 0, 0};
        const float* xrow = xs + f * FFT_N * XSP + cq * 4;
        for (int t = 0; t < FFT_N; ++t) {
            float4 xv = *(const float4*)(xrow + t * XSP);
            float xc[4] = {xv.x, xv.y, xv.z, xv.w};
            #pragma unroll
            for (int kk = 0; kk < 4; ++kk) {
                float2 tw = cst[idx[kk]];
                idx[kk] = (idx[kk] + k0 + kk) & (FFT_N - 1);
                #pragma unroll
                for (int cc = 0; cc < 4; ++cc) {
                    accr[kk][cc] = fmaf(xc[cc], tw.x, accr[kk][cc]);
                    acci[kk][cc] = fmaf(xc[cc], tw.y, acci[kk][cc]);
                }
            }
        }
        #pragma unroll
        for (int kk = 0; kk < 4; ++kk) {
            int k = k0 + kk;
            if (k < BINS) {
                #pragma unroll
                for (int cc = 0; cc < 4; ++cc)
                    xf2[(f * BINS + k) * CP + cq * 4 + cc] =
                        make_float2(accr[kk][cc], -acci[kk][cc]);
            }
        }
    }
    __syncthreads();

    constexpr int NT_MM = BINS * 8;
    for (int task = tid; task < NT_MM; task += 256) {
        int oq = task & 7, k = task >> 3;
        float2 accY[NFR][4] = {};
        float w1 = 0.f; int i0 = 0, i1 = 0;
        if (!USE_WS) {
            float s  = (k + 0.5f) * (33.0f / BINS) - 0.5f;
            float fl = floorf(s); w1 = s - fl;
            i0 = min(max((int)fl, 0), 32);
            i1 = min(max((int)fl + 1, 0), 32);
        }
        const uint32_t* wp = USE_WS ? (wsu + WSP + k * 2048 + oq * 4) : (const uint32_t*)nullptr;
        for (int c = 0; c < CIN; ++c) {
            float krv[4], kiv[4];
            if (USE_WS) {
                uint4 u = *(const uint4*)(wp + c * 32);
                krv[0] = lo_bf(u.x); kiv[0] = hi_bf(u.x);
                krv[1] = lo_bf(u.y); kiv[1] = hi_bf(u.y);
                krv[2] = lo_bf(u.z); kiv[2] = hi_bf(u.z);
                krv[3] = lo_bf(u.w); kiv[3] = hi_bf(u.w);
            } else {
                const float* p = kr + (size_t)i0 * 2048 + c * 32 + oq * 4;
                const float* q = kr + (size_t)i1 * 2048 + c * 32 + oq * 4;
                float4 r0 = *(const float4*)p, r1 = *(const float4*)q;
                p = ki + (size_t)i0 * 2048 + c * 32 + oq * 4;
                q = ki + (size_t)i1 * 2048 + c * 32 + oq * 4;
                float4 q0 = *(const float4*)p, q1 = *(const float4*)q;
                krv[0] = fmaf(w1, r1.x - r0.x, r0.x); kiv[0] = fmaf(w1, q1.x - q0.x, q0.x);
                krv[1] = fmaf(w1, r1.y - r0.y, r0.y); kiv[1] = fmaf(w1, q1.y - q0.y, q0.y);
                krv[2] = fmaf(w1, r1.z - r0.z, r0.z); kiv[2] = fmaf(w1, q1.z - q0.z, q0.z);
                krv[3] = fmaf(w1, r1.w - r0.w, r0.w); kiv[3] = fmaf(w1, q1.w - q0.w, q0.w);
            }
            #pragma unroll
            for (int f = 0; f < NFR; ++f) {
                float2 xv = xf2[(f * BINS + k) * CP + c];
                #pragma unroll
                for (int jo = 0; jo < 4; ++jo) {
                    accY[f][jo].x += xv.x * krv[jo] - xv.y * kiv[jo];
                    accY[f][jo].y += xv.x * kiv[jo] + xv.y * krv[jo];
                }
            }
        }
        float wk = (k == 0 || k == BINS - 1) ? (1.0f / FFT_N) : (2.0f / FFT_N);
        #pragma unroll
        for (int f = 0; f < NFR; ++f) {
            #pragma unroll
            for (int jo = 0; jo < 4; ++jo) {
                float yr = accY[f][jo].x; yr = (yr > 0.f) ? yr : 0.2f * yr;
                float yi = accY[f][jo].y; yi = (yi > 0.f) ? yi : 0.2f * yi;
                Y2[(f * COUT + oq * 4 + jo) * YP + k] = make_float2(yr * wk, yi * wk);
            }
        }
    }
    __syncthreads();

    {
        int tq = tid >> 3, oq = tid & 7;
        int tg0 = tq * 4;
        int f   = tg0 / FFT_N;
        int tl0 = tg0 % FFT_N;
        float acc[4][4] = {};
        int idx[4] = {0, 0, 0, 0};
        const float2* yb = Y2 + (f * COUT + oq * 4) * YP;
        for (int k = 0; k < BINS; ++k) {
            float2 tw[4];
            #pragma unroll
            for (int j = 0; j < 4; ++j) {
                tw[j] = cst[idx[j]];
                idx[j] = (idx[j] + tl0 + j) & (FFT_N - 1);
            }
            #pragma unroll
            for (int jo = 0; jo < 4; ++jo) {
                float2 yv = yb[jo * YP + k];
                #pragma unroll
                for (int j = 0; j < 4; ++j)
                    acc[j][jo] += yv.x * tw[j].x - yv.y * tw[j].y;
            }
        }
        float4 bv = *(const float4*)(bias + COFF + oq * 4);
        float* ob = out + ((size_t)(b * T_SZ + w * 128 + tg0)) * NCH + COFF + oq * 4;
        #pragma unroll
        for (int j = 0; j < 4; ++j) {
            float4 o4 = make_float4(acc[j][0] + bv.x, acc[j][1] + bv.y,
                                    acc[j][2] + bv.z, acc[j][3] + bv.w);
            *(float4*)(ob + (size_t)j * NCH) = o4;
        }
    }
}

// =============================== launch ========================================
extern "C" void kernel_launch(void* const* d_in, const int* in_sizes, int n_in,
                              void* d_out, int out_size, void* d_ws, size_t ws_size,
                              hipStream_t stream)
{
    (void)in_sizes; (void)n_in; (void)out_size;
    const float* x    = (const float*)d_in[0];
    const float* kr   = (const float*)d_in[1];
    const float* ki   = (const float*)d_in[2];
    const float* bias = (const float*)d_in[3];
    float* out = (float*)d_out;
    char* ws = (char*)d_ws;
    dim3 blk(256);

    if (ws != nullptr && ws_size >= (size_t)WS_WIDE) {
        prep_full<<<dim3(226), blk, 0, stream>>>(ws);
        k1w   <<<dim3(512),  dim3(512), 0, stream>>>(x, ws);
        k2all <<<dim3(796),  blk, 0, stream>>>(kr, ki, ws);
        k3all <<<dim3(1024), blk, 0, stream>>>(ws, bias, out);
    } else if (ws != nullptr && ws_size >= (size_t)WS_TOTAL_PAIRS * 4) {
        uint32_t* wsu = (uint32_t*)ws;
        prep_resize<<<dim3(920), blk, 0, stream>>>(kr, ki, wsu);
        stft_fused<32,  true><<<dim3(512), blk, 0, stream>>>(x, kr, ki, bias, wsu, out);
        stft_fused<64,  true><<<dim3(512), blk, 0, stream>>>(x, kr, ki, bias, wsu, out);
        stft_fused<128, true><<<dim3(512), blk, 0, stream>>>(x, kr, ki, bias, wsu, out);
    } else {
        stft_fused<32,  false><<<dim3(512), blk, 0, stream>>>(x, kr, ki, bias, nullptr, out);
        stft_fused<64,  false><<<dim3(512), blk, 0, stream>>>(x, kr, ki, bias, nullptr, out);
        stft_fused<128, false><<<dim3(512), blk, 0, stream>>>(x, kr, ki, bias, nullptr, out);
    }
}